// Round 9
// baseline (89.400 us; speedup 1.0000x reference)
//
#include <hip/hip_runtime.h>

typedef float  f32x4  __attribute__((ext_vector_type(4)));
typedef float  f32x2  __attribute__((ext_vector_type(2)));
typedef short  bf16x8 __attribute__((ext_vector_type(8)));
typedef int    i32x4  __attribute__((ext_vector_type(4)));

#define NNODE 3072
#define DIN   128
#define DOUT  128
#define NREL  3
#define NH    4
#define HD    32
#define KCH   48      // K chunks of 64
#define CHP   10240   // PADDED ushorts per B chunk (20480 B = 5 x 4KB stage units; 9216 real)

static __device__ __forceinline__ unsigned short f2bf(float v) {
  unsigned u = __builtin_bit_cast(unsigned, v);
  u += 0x7FFFu + ((u >> 16) & 1u);          // round-to-nearest-even
  return (unsigned short)(u >> 16);
}

// ---------------- K0: init out = bias ----------------
__global__ __launch_bounds__(256, 1) void k0_init(
    const float* __restrict__ bias, float* __restrict__ out)
{
  const int tid = blockIdx.x * 256 + threadIdx.x;   // 3072*128/4 elems
  f32x4 b = *(const f32x4*)(bias + (tid & 31) * 4);
  *((f32x4*)out + tid) = b;
}

// ---------------- K1: t = F * W_r^T, attention scalars, build B in MFMA-fragment order ----
// grid (48, 3), block 256. (numerics validated R2-R8; only chunk stride changed to CHP)
__global__ __launch_bounds__(256, 1) void k1_prep(
    const float* __restrict__ feat, const float* __restrict__ W,
    const float* __restrict__ av, unsigned short* __restrict__ Mt,
    float* __restrict__ Es)
{
  const int jt = blockIdx.x;     // 0..47  (= K chunk index)
  const int r  = blockIdx.y;     // 0..2
  const int t  = threadIdx.x;    // 0..255
  const int jb = jt * 64;

  __shared__ float Wl[128 * 130];
  __shared__ float Fl[64 * 129];
  __shared__ float Tl[64 * 129];
  __shared__ float El[64 * 5];

  const float* Wr = W + r * DOUT * DIN;
  for (int idx = t * 4; idx < DOUT * DIN; idx += 1024) {
    float4 v = *(const float4*)(Wr + idx);
    int o = idx >> 7, k = idx & 127;
    float* d = Wl + o * 130 + k;
    d[0] = v.x; d[1] = v.y; d[2] = v.z; d[3] = v.w;
  }
  for (int idx = t * 4; idx < 64 * DIN; idx += 1024) {
    float4 v = *(const float4*)(feat + (size_t)jb * DIN + idx);
    int n = idx >> 7, k = idx & 127;
    float* d = Fl + n * 129 + k;
    d[0] = v.x; d[1] = v.y; d[2] = v.z; d[3] = v.w;
  }
  __syncthreads();

  {
    const int ng = t & 15, og = t >> 4;
    float acc[4][8] = {};
    for (int k = 0; k < DIN; k += 4) {
      float wv[4][8];
      #pragma unroll
      for (int oo = 0; oo < 8; ++oo) {
        const float* wr2 = Wl + (og * 8 + oo) * 130 + k;
        f32x2 a01 = *(const f32x2*)wr2;
        f32x2 a23 = *(const f32x2*)(wr2 + 2);
        wv[0][oo] = a01[0]; wv[1][oo] = a01[1];
        wv[2][oo] = a23[0]; wv[3][oo] = a23[1];
      }
      #pragma unroll
      for (int nn = 0; nn < 4; ++nn) {
        const float* fr = Fl + (ng * 4 + nn) * 129 + k;
        float f0 = fr[0], f1 = fr[1], f2 = fr[2], f3 = fr[3];
        #pragma unroll
        for (int oo = 0; oo < 8; ++oo) {
          float s = acc[nn][oo];
          s = fmaf(f0, wv[0][oo], s);
          s = fmaf(f1, wv[1][oo], s);
          s = fmaf(f2, wv[2][oo], s);
          s = fmaf(f3, wv[3][oo], s);
          acc[nn][oo] = s;
        }
      }
    }
    #pragma unroll
    for (int nn = 0; nn < 4; ++nn)
      #pragma unroll
      for (int oo = 0; oo < 8; ++oo)
        Tl[(ng * 4 + nn) * 129 + og * 8 + oo] = acc[nn][oo];
  }
  __syncthreads();

  {
    const int n = t & 63, h = t >> 6;
    const float* tr = Tl + n * 129 + h * HD;
    const float* as = av + r * 2 * HD;
    float ss = 0.f, sd = 0.f;
    #pragma unroll
    for (int d = 0; d < HD; ++d) {
      float tvv = tr[d];
      ss = fmaf(tvv, as[d],      ss);
      sd = fmaf(tvv, as[HD + d], sd);
    }
    Es[((size_t)r * NNODE + jb + n) * NH + h] = expf(ss);
    El[n * 5 + h] = expf(sd);
  }
  __syncthreads();

  {
    // B fragment order: chunk = [tile nt][step s][lane = k8*16 + (c&15)][elem = j&7]
    const int n = t & 63, cb = t >> 6;   // j = jb + n
    unsigned short* base = Mt + ((size_t)r * KCH + jt) * CHP;
    const int s = n >> 5, k8 = (n >> 3) & 3, elem = n & 7;
    const int lanebase = k8 * 16;
    #pragma unroll
    for (int ci = 0; ci < 36; ++ci) {
      int c = cb * 36 + ci;
      float v;
      if (c < DOUT)            v = Tl[n * 129 + c] * El[n * 5 + (c >> 5)];
      else if (c < DOUT + NH)  v = El[n * 5 + (c - DOUT)];
      else if (c == DOUT + NH) v = 1.0f;
      else                     v = 0.0f;
      int nt = c >> 4;
      base[(nt * 2 + s) * 512 + (lanebase + (c & 15)) * 8 + elem] = f2bf(v);
    }
  }
}

// ---------------- K2a: bit-pack adjacency (113 MB -> 3.5 MB), 6-deep load ILP ----------------
// grid 2048, block 256. 8192 waves x 54 units; unit = one 64-col span of one row.
__global__ __launch_bounds__(256) void k2a_pack(
    const int* __restrict__ adj, unsigned int* __restrict__ pk)
{
  const int wgid = blockIdx.x * 4 + (threadIdx.x >> 6);
  const int l = threadIdx.x & 63;
  #pragma unroll 1
  for (int i = 0; i < 54; i += 6) {
    int a[6], rr[6], cc[6];
    #pragma unroll
    for (int q = 0; q < 6; ++q) {
      const int u = (i + q) * 8192 + wgid;       // 0..442367
      rr[q] = u / 48; cc[q] = u - rr[q] * 48;
      a[q] = adj[(size_t)rr[q] * NNODE + cc[q] * 64 + l];
    }
    #pragma unroll
    for (int q = 0; q < 6; ++q) {
      unsigned long long m = __ballot(a[q] != 0);
      if (l == 0)
        *(unsigned long long*)(pk + (size_t)rr[q] * 96 + cc[q] * 2) = m;
    }
  }
}

// ---------------- K2b: bitpacked-A GEMM, m201-style LDS B pipeline, fused finalize ----------
// grid (96, 3), block 256 = 4 waves. Block: 32 rows x 144 cols, full K.
// A: 12.4KB packed bits, LDS-resident from prologue (zero loop traffic).
// B: 3 x 20KB LDS buffers, staged via 5 uniform global_load_lds(16B)/thread/chunk;
// one raw s_barrier + counted vmcnt(5) per iter (never 0 in loop).
#define EXPAND(d, dst) do {                                                \
    unsigned b_  = ((d) >> sh) & 0xFFu;                                    \
    unsigned lo_ = ((b_ & 0x0Fu) * 0x204081u) & 0x01010101u;               \
    unsigned hi_ = ((b_ >> 4)   * 0x204081u) & 0x01010101u;                \
    dst = __builtin_bit_cast(bf16x8, (i32x4){                              \
      (int)(__builtin_amdgcn_perm(0u, lo_, 0x0C010C00u) * 0x3F80u),        \
      (int)(__builtin_amdgcn_perm(0u, lo_, 0x0C030C02u) * 0x3F80u),        \
      (int)(__builtin_amdgcn_perm(0u, hi_, 0x0C010C00u) * 0x3F80u),        \
      (int)(__builtin_amdgcn_perm(0u, hi_, 0x0C030C02u) * 0x3F80u)});      \
  } while (0)

#define MF(a, b, c) __builtin_amdgcn_mfma_f32_16x16x32_bf16(a, b, c, 0, 0, 0)

__global__ __launch_bounds__(256, 2) void k2b_agg(
    const unsigned int* __restrict__ pk, const unsigned short* __restrict__ Mt,
    const float* __restrict__ Es, float* __restrict__ out)
{
  const int it = blockIdx.x;    // 0..95
  const int r  = blockIdx.y;    // 0..2
  const int t  = threadIdx.x;   // 0..255
  const int wv = t >> 6;
  const int l  = t & 63;
  const int l16 = l & 15, l4 = l >> 4;
  const int ib = it * 32;
  const bool w3 = (wv == 3);
  const unsigned sh = (unsigned)l4 * 8u;

  __shared__ __align__(16) unsigned Al[32 * 97];            // 12416 B, bank-padded
  __shared__ __align__(16) unsigned short Bl[3][CHP];       // 61440 B
  float* red   = (float*)&Bl[0][0];                         // epilogue overlay on buf0
  float* coefL = red + 32 * 145;                            // 18560+512 B < 20480 B

  // ---- prologue: packed A row-block (all K) into LDS once ----
  {
    const unsigned* pg = pk + ((size_t)r * NNODE + ib) * 96;
    #pragma unroll
    for (int x = 0; x < 12; ++x) {
      int idx = t + x * 256;
      Al[(idx / 96) * 97 + (idx % 96)] = pg[idx];
    }
  }

  const unsigned short* msrc = Mt + (size_t)r * KCH * CHP;
  #define STAGE_B(kc, buf) do {                                                   \
    const unsigned short* s_ = msrc + (size_t)(kc) * CHP;                         \
    _Pragma("unroll")                                                             \
    for (int j_ = 0; j_ < 5; ++j_)                                                \
      __builtin_amdgcn_global_load_lds(                                           \
        (const __attribute__((address_space(1))) void*)(s_ + j_ * 2048 + t * 8),  \
        (__attribute__((address_space(3))) void*)&Bl[buf][j_ * 2048 + t * 8],     \
        16, 0, 0);                                                                \
  } while (0)

  f32x4 acc00 = {}, acc01 = {}, acc10 = {}, acc11 = {}, acc20 = {}, acc21 = {};
  const int tb = wv * 2;     // col-tiles {tb, tb+1}; wave 3 also tile 8 (V/deg)

  STAGE_B(0, 0);
  asm volatile("s_waitcnt vmcnt(0)");
  __syncthreads();           // A + chunk0 resident

  #pragma unroll 1
  for (int k = 0; k < KCH; ++k) {
    const int nk = (k + 1 < KCH) ? k + 1 : KCH - 1;
    STAGE_B(nk, (k + 1) % 3);
    __builtin_amdgcn_sched_barrier(0);
    asm volatile("s_waitcnt vmcnt(5)");      // chunk k's 5 done; chunk k+1's 5 in flight
    __builtin_amdgcn_s_barrier();
    __builtin_amdgcn_sched_barrier(0);

    const unsigned short* Bc = &Bl[k % 3][0];
    const unsigned d0 = Al[l16 * 97 + 2 * k],        d1 = Al[l16 * 97 + 2 * k + 1];
    const unsigned e0 = Al[(16 + l16) * 97 + 2 * k], e1 = Al[(16 + l16) * 97 + 2 * k + 1];
    bf16x8 af0, af1;

    // step 0 (k-bits 64k .. 64k+31)
    EXPAND(d0, af0); EXPAND(e0, af1);
    {
      bf16x8 b0 = *(const bf16x8*)(Bc + ((tb + 0) * 2 + 0) * 512 + l * 8);
      bf16x8 b1 = *(const bf16x8*)(Bc + ((tb + 1) * 2 + 0) * 512 + l * 8);
      acc00 = MF(af0, b0, acc00); acc01 = MF(af1, b0, acc01);
      acc10 = MF(af0, b1, acc10); acc11 = MF(af1, b1, acc11);
      if (w3) {
        bf16x8 b2 = *(const bf16x8*)(Bc + (8 * 2 + 0) * 512 + l * 8);
        acc20 = MF(af0, b2, acc20); acc21 = MF(af1, b2, acc21);
      }
    }
    // step 1 (k-bits 64k+32 .. 64k+63)
    EXPAND(d1, af0); EXPAND(e1, af1);
    {
      bf16x8 b0 = *(const bf16x8*)(Bc + ((tb + 0) * 2 + 1) * 512 + l * 8);
      bf16x8 b1 = *(const bf16x8*)(Bc + ((tb + 1) * 2 + 1) * 512 + l * 8);
      acc00 = MF(af0, b0, acc00); acc01 = MF(af1, b0, acc01);
      acc10 = MF(af0, b1, acc10); acc11 = MF(af1, b1, acc11);
      if (w3) {
        bf16x8 b2 = *(const bf16x8*)(Bc + (8 * 2 + 1) * 512 + l * 8);
        acc20 = MF(af0, b2, acc20); acc21 = MF(af1, b2, acc21);
      }
    }
  }

  // drain dummy stage (it targeted buf0 = red overlay), then reuse LDS
  asm volatile("s_waitcnt vmcnt(0)");
  __syncthreads();

  // ---- epilogue: disjoint col-tiles -> plain LDS writes, coef, atomic out ----
  #pragma unroll
  for (int j = 0; j < 4; ++j) {
    red[(l4 * 4 + j) * 145 + (tb + 0) * 16 + l16]      = acc00[j];
    red[(16 + l4 * 4 + j) * 145 + (tb + 0) * 16 + l16] = acc01[j];
    red[(l4 * 4 + j) * 145 + (tb + 1) * 16 + l16]      = acc10[j];
    red[(16 + l4 * 4 + j) * 145 + (tb + 1) * 16 + l16] = acc11[j];
    if (w3) {
      red[(l4 * 4 + j) * 145 + 8 * 16 + l16]      = acc20[j];
      red[(16 + l4 * 4 + j) * 145 + 8 * 16 + l16] = acc21[j];
    }
  }
  __syncthreads();

  if (t < 128) {
    int row = t >> 2, h = t & 3;
    float es = Es[((size_t)r * NNODE + ib + row) * NH + h];
    float V  = red[row * 145 + DOUT + h];
    float dg = red[row * 145 + DOUT + NH];
    coefL[t] = es / fmaf(es, V, (float)NNODE - dg) * (1.0f / NREL);
  }
  __syncthreads();

  #pragma unroll
  for (int idx = t; idx < 32 * DOUT; idx += 256) {
    int row = idx >> 7, c = idx & 127;
    atomicAdd(&out[(size_t)(ib + row) * DOUT + c],
              coefL[row * 4 + (c >> 5)] * red[row * 145 + c]);
  }
  #undef STAGE_B
}

extern "C" void kernel_launch(void* const* d_in, const int* in_sizes, int n_in,
                              void* d_out, int out_size, void* d_ws, size_t ws_size,
                              hipStream_t stream) {
  const float* feat = (const float*)d_in[0];
  const int*   adj  = (const int*)d_in[1];
  const float* W    = (const float*)d_in[2];
  const float* av   = (const float*)d_in[3];
  const float* bias = (const float*)d_in[4];

  char* ws = (char*)d_ws;
  unsigned short* Mt = (unsigned short*)ws;                 // 3*48*10240*2 = 2,949,120 B
  float* Es = (float*)(ws + 2949120);                       // 3*3072*4*4   =   147,456 B
  unsigned int* pk = (unsigned int*)(ws + 3096576);         // 9216*96*4    = 3,538,944 B
                                                            // total ws use: 6,635,520 B

  hipLaunchKernelGGL(k0_init,  dim3(384), dim3(256), 0, stream, bias, (float*)d_out);
  hipLaunchKernelGGL(k1_prep,  dim3(48, 3), dim3(256), 0, stream, feat, W, av, Mt, Es);
  hipLaunchKernelGGL(k2a_pack, dim3(2048), dim3(256), 0, stream, adj, pk);
  hipLaunchKernelGGL(k2b_agg,  dim3(96, 3), dim3(256), 0, stream, pk, Mt, Es, (float*)d_out);
}

// Round 10
// 85.903 us; speedup vs baseline: 1.0407x; 1.0407x over previous
//
#include <hip/hip_runtime.h>

typedef float  f32x4  __attribute__((ext_vector_type(4)));
typedef float  f32x2  __attribute__((ext_vector_type(2)));
typedef short  bf16x8 __attribute__((ext_vector_type(8)));
typedef int    i32x4  __attribute__((ext_vector_type(4)));

#define NNODE 3072
#define DIN   128
#define DOUT  128
#define NREL  3
#define NH    4
#define HD    32
#define KCH   48      // K chunks of 64
#define CHP   10240   // padded ushorts per B chunk (20480 B = 5 x 4KB stage units; 9216 real)

static __device__ __forceinline__ unsigned short f2bf(float v) {
  unsigned u = __builtin_bit_cast(unsigned, v);
  u += 0x7FFFu + ((u >> 16) & 1u);          // round-to-nearest-even
  return (unsigned short)(u >> 16);
}

// ---------------- K0: zero Cws (atomic accumulator; ws is poisoned 0xAA) ----------------
__global__ __launch_bounds__(256, 1) void k0_zero(float* __restrict__ Cws)
{
  ((f32x4*)Cws)[blockIdx.x * 256 + threadIdx.x] = (f32x4){0.f, 0.f, 0.f, 0.f};
}

// ---------------- K1: t = F * W_r^T, attention scalars, build B in MFMA-fragment order ----
// grid (48, 3), block 256. (numerics validated R2-R9)
__global__ __launch_bounds__(256, 1) void k1_prep(
    const float* __restrict__ feat, const float* __restrict__ W,
    const float* __restrict__ av, unsigned short* __restrict__ Mt,
    float* __restrict__ Es)
{
  const int jt = blockIdx.x;     // 0..47  (= K chunk index)
  const int r  = blockIdx.y;     // 0..2
  const int t  = threadIdx.x;    // 0..255
  const int jb = jt * 64;

  __shared__ float Wl[128 * 130];
  __shared__ float Fl[64 * 129];
  __shared__ float Tl[64 * 129];
  __shared__ float El[64 * 5];

  const float* Wr = W + r * DOUT * DIN;
  for (int idx = t * 4; idx < DOUT * DIN; idx += 1024) {
    float4 v = *(const float4*)(Wr + idx);
    int o = idx >> 7, k = idx & 127;
    float* d = Wl + o * 130 + k;
    d[0] = v.x; d[1] = v.y; d[2] = v.z; d[3] = v.w;
  }
  for (int idx = t * 4; idx < 64 * DIN; idx += 1024) {
    float4 v = *(const float4*)(feat + (size_t)jb * DIN + idx);
    int n = idx >> 7, k = idx & 127;
    float* d = Fl + n * 129 + k;
    d[0] = v.x; d[1] = v.y; d[2] = v.z; d[3] = v.w;
  }
  __syncthreads();

  {
    const int ng = t & 15, og = t >> 4;
    float acc[4][8] = {};
    for (int k = 0; k < DIN; k += 4) {
      float wv[4][8];
      #pragma unroll
      for (int oo = 0; oo < 8; ++oo) {
        const float* wr2 = Wl + (og * 8 + oo) * 130 + k;
        f32x2 a01 = *(const f32x2*)wr2;
        f32x2 a23 = *(const f32x2*)(wr2 + 2);
        wv[0][oo] = a01[0]; wv[1][oo] = a01[1];
        wv[2][oo] = a23[0]; wv[3][oo] = a23[1];
      }
      #pragma unroll
      for (int nn = 0; nn < 4; ++nn) {
        const float* fr = Fl + (ng * 4 + nn) * 129 + k;
        float f0 = fr[0], f1 = fr[1], f2 = fr[2], f3 = fr[3];
        #pragma unroll
        for (int oo = 0; oo < 8; ++oo) {
          float s = acc[nn][oo];
          s = fmaf(f0, wv[0][oo], s);
          s = fmaf(f1, wv[1][oo], s);
          s = fmaf(f2, wv[2][oo], s);
          s = fmaf(f3, wv[3][oo], s);
          acc[nn][oo] = s;
        }
      }
    }
    #pragma unroll
    for (int nn = 0; nn < 4; ++nn)
      #pragma unroll
      for (int oo = 0; oo < 8; ++oo)
        Tl[(ng * 4 + nn) * 129 + og * 8 + oo] = acc[nn][oo];
  }
  __syncthreads();

  {
    const int n = t & 63, h = t >> 6;
    const float* tr = Tl + n * 129 + h * HD;
    const float* as = av + r * 2 * HD;
    float ss = 0.f, sd = 0.f;
    #pragma unroll
    for (int d = 0; d < HD; ++d) {
      float tvv = tr[d];
      ss = fmaf(tvv, as[d],      ss);
      sd = fmaf(tvv, as[HD + d], sd);
    }
    Es[((size_t)r * NNODE + jb + n) * NH + h] = expf(ss);
    El[n * 5 + h] = expf(sd);
  }
  __syncthreads();

  {
    // B fragment order: chunk = [tile nt][step s][lane = k8*16 + (c&15)][elem = j&7]
    const int n = t & 63, cb = t >> 6;   // j = jb + n
    unsigned short* base = Mt + ((size_t)r * KCH + jt) * CHP;
    const int s = n >> 5, k8 = (n >> 3) & 3, elem = n & 7;
    const int lanebase = k8 * 16;
    #pragma unroll
    for (int ci = 0; ci < 36; ++ci) {
      int c = cb * 36 + ci;
      float v;
      if (c < DOUT)            v = Tl[n * 129 + c] * El[n * 5 + (c >> 5)];
      else if (c < DOUT + NH)  v = El[n * 5 + (c - DOUT)];
      else if (c == DOUT + NH) v = 1.0f;
      else                     v = 0.0f;
      int nt = c >> 4;
      base[(nt * 2 + s) * 512 + (lanebase + (c & 15)) * 8 + elem] = f2bf(v);
    }
  }
}

// ---------------- K2a: bit-pack adjacency (113 MB -> 3.5 MB), 9-deep load ILP ----------------
// grid 2048, block 256. 8192 waves x 54 units; unit = one 64-col span of one flat row.
__global__ __launch_bounds__(256) void k2a_pack(
    const int* __restrict__ adj, unsigned int* __restrict__ pk)
{
  const int wgid = blockIdx.x * 4 + (threadIdx.x >> 6);
  const int l = threadIdx.x & 63;
  #pragma unroll 1
  for (int i = 0; i < 54; i += 9) {
    int a[9], rr[9], cc[9];
    #pragma unroll
    for (int q = 0; q < 9; ++q) {
      const int u = (i + q) * 8192 + wgid;       // 0..442367 (9216 rows x 48 spans)
      rr[q] = u / 48; cc[q] = u - rr[q] * 48;
      a[q] = adj[(size_t)rr[q] * NNODE + cc[q] * 64 + l];
    }
    #pragma unroll
    for (int q = 0; q < 9; ++q) {
      unsigned long long m = __ballot(a[q] != 0);
      if (l == 0)
        *(unsigned long long*)(pk + (size_t)rr[q] * 96 + cc[q] * 2) = m;
    }
  }
}

// ---------------- K2b: bitpacked-A GEMM, M=128/K-split-3, LDS B pipeline, atomic Cws ------
// grid (24, 3, 3), block 256 = 4 waves. Block: 128 rows x 144 cols x 16 chunks.
// A bits: 18.4KB LDS, loaded once. B: 3 x 20KB LDS buffers, 5 x global_load_lds/thread/chunk,
// counted vmcnt(5) + raw s_barrier per chunk (never vmcnt(0) in loop). Wave wv owns rows
// [wv*32, +32), all 9 col-tiles (acc[2][9] f32x4). Epilogue: atomicAdd partials into Cws.
#define EXPAND(d, dst) do {                                                \
    unsigned b_  = ((d) >> sh) & 0xFFu;                                    \
    unsigned lo_ = ((b_ & 0x0Fu) * 0x204081u) & 0x01010101u;               \
    unsigned hi_ = ((b_ >> 4)   * 0x204081u) & 0x01010101u;                \
    dst = __builtin_bit_cast(bf16x8, (i32x4){                              \
      (int)(__builtin_amdgcn_perm(0u, lo_, 0x0C010C00u) * 0x3F80u),        \
      (int)(__builtin_amdgcn_perm(0u, lo_, 0x0C030C02u) * 0x3F80u),        \
      (int)(__builtin_amdgcn_perm(0u, hi_, 0x0C010C00u) * 0x3F80u),        \
      (int)(__builtin_amdgcn_perm(0u, hi_, 0x0C030C02u) * 0x3F80u)});      \
  } while (0)

#define MF(a, b, c) __builtin_amdgcn_mfma_f32_16x16x32_bf16(a, b, c, 0, 0, 0)

__global__ __launch_bounds__(256, 2) void k2b_agg(
    const unsigned int* __restrict__ pk, const unsigned short* __restrict__ Mt,
    float* __restrict__ Cws)
{
  const int mt = blockIdx.x;    // 0..23  M-tile
  const int kq = blockIdx.y;    // 0..2   K-third (16 chunks)
  const int r  = blockIdx.z;    // 0..2
  const int t  = threadIdx.x;   // 0..255
  const int wv = t >> 6;
  const int l  = t & 63;
  const int l16 = l & 15, l4 = l >> 4;
  const int ib = mt * 128;
  const unsigned sh = (unsigned)l4 * 8u;

  __shared__ __align__(16) unsigned Al[128 * 36];           // 18432 B (row pad 36: 16B-aligned rows)
  __shared__ __align__(16) unsigned short Bl[3][CHP];       // 61440 B

  // ---- prologue: A bits, rows ib..ib+127, uints [kq*32, +32) per row ----
  {
    const unsigned* pg = pk + ((size_t)r * NNODE + ib) * 96 + kq * 32;
    const int ri = t >> 1, half = (t & 1) * 16;
    const unsigned* src = pg + (size_t)ri * 96 + half;
    #pragma unroll
    for (int q = 0; q < 4; ++q)
      *(i32x4*)&Al[ri * 36 + half + q * 4] = *(const i32x4*)(src + q * 4);
  }

  const unsigned short* msrc = Mt + ((size_t)r * KCH + (size_t)kq * 16) * CHP;
  #define STAGE_B(kk, buf) do {                                                   \
    const unsigned short* s_ = msrc + (size_t)(kk) * CHP;                         \
    _Pragma("unroll")                                                             \
    for (int j_ = 0; j_ < 5; ++j_)                                                \
      __builtin_amdgcn_global_load_lds(                                           \
        (const __attribute__((address_space(1))) void*)(s_ + j_ * 2048 + t * 8),  \
        (__attribute__((address_space(3))) void*)&Bl[buf][j_ * 2048 + t * 8],     \
        16, 0, 0);                                                                \
  } while (0)

  f32x4 acc[2][9] = {};

  STAGE_B(0, 0);
  asm volatile("s_waitcnt vmcnt(0)");
  __syncthreads();           // A + chunk0 resident

  #pragma unroll 1
  for (int kk = 0; kk < 16; ++kk) {
    const int nk = (kk + 1 < 16) ? kk + 1 : 15;
    STAGE_B(nk, (kk + 1) % 3);
    __builtin_amdgcn_sched_barrier(0);
    asm volatile("s_waitcnt vmcnt(5)");      // chunk kk's 5 done; chunk kk+1's 5 in flight
    __builtin_amdgcn_s_barrier();
    __builtin_amdgcn_sched_barrier(0);

    const unsigned short* Bc = &Bl[kk % 3][0];
    const unsigned d0 = Al[(wv * 32 + l16) * 36 + 2 * kk];
    const unsigned d1 = Al[(wv * 32 + l16) * 36 + 2 * kk + 1];
    const unsigned e0 = Al[(wv * 32 + 16 + l16) * 36 + 2 * kk];
    const unsigned e1 = Al[(wv * 32 + 16 + l16) * 36 + 2 * kk + 1];
    bf16x8 af0, af1;

    // step 0 (k-bits 64kk .. +31)
    EXPAND(d0, af0); EXPAND(e0, af1);
    #pragma unroll
    for (int nt = 0; nt < 9; ++nt) {
      bf16x8 b = *(const bf16x8*)(Bc + (nt * 2 + 0) * 512 + l * 8);
      acc[0][nt] = MF(af0, b, acc[0][nt]);
      acc[1][nt] = MF(af1, b, acc[1][nt]);
    }
    // step 1 (k-bits 64kk+32 .. +63)
    EXPAND(d1, af0); EXPAND(e1, af1);
    #pragma unroll
    for (int nt = 0; nt < 9; ++nt) {
      bf16x8 b = *(const bf16x8*)(Bc + (nt * 2 + 1) * 512 + l * 8);
      acc[0][nt] = MF(af0, b, acc[0][nt]);
      acc[1][nt] = MF(af1, b, acc[1][nt]);
    }
  }
  asm volatile("s_waitcnt vmcnt(0)");   // retire dummy stage before exit

  // ---- epilogue: atomic partials into Cws (row = ib + wv*32 + h*16 + l4*4 + j) ----
  float* base = Cws + ((size_t)r * NNODE + ib + wv * 32) * 144;
  #pragma unroll
  for (int h = 0; h < 2; ++h)
    #pragma unroll
    for (int nt = 0; nt < 9; ++nt)
      #pragma unroll
      for (int j = 0; j < 4; ++j)
        atomicAdd(&base[(size_t)(h * 16 + l4 * 4 + j) * 144 + nt * 16 + l16],
                  acc[h][nt][j]);
  #undef STAGE_B
}

// ---------------- K3: finalize coef + mean + bias (R2-validated math) ----------------
// grid 3072, block 128: one output row per block.
__global__ __launch_bounds__(128, 1) void k3_final(
    const float* __restrict__ Cws, const float* __restrict__ Es,
    const float* __restrict__ bias, float* __restrict__ out)
{
  const int i = blockIdx.x;
  const int t = threadIdx.x;
  __shared__ float coef[12];
  if (t < 12) {
    int r = t >> 2, h = t & 3;
    const float* Ci = Cws + ((size_t)r * NNODE + i) * 144;
    float es = Es[((size_t)r * NNODE + i) * NH + h];
    float V  = Ci[DOUT + h];
    float dg = Ci[DOUT + NH];
    coef[t] = es / fmaf(es, V, (float)NNODE - dg) * (1.0f / NREL);
  }
  __syncthreads();
  const int h = t >> 5;
  float s = 0.f;
  #pragma unroll
  for (int r = 0; r < 3; ++r)
    s += coef[r * 4 + h] * Cws[((size_t)r * NNODE + i) * 144 + t];
  out[(size_t)i * DOUT + t] = s + bias[t];
}

extern "C" void kernel_launch(void* const* d_in, const int* in_sizes, int n_in,
                              void* d_out, int out_size, void* d_ws, size_t ws_size,
                              hipStream_t stream) {
  const float* feat = (const float*)d_in[0];
  const int*   adj  = (const int*)d_in[1];
  const float* W    = (const float*)d_in[2];
  const float* av   = (const float*)d_in[3];
  const float* bias = (const float*)d_in[4];

  char* ws = (char*)d_ws;
  unsigned short* Mt = (unsigned short*)ws;                 // 3*48*10240*2 = 2,949,120 B
  float* Es          = (float*)(ws + 2949120);              // 3*3072*4*4   =   147,456 B
  unsigned int* pk   = (unsigned int*)(ws + 3096576);       // 9216*96*4    = 3,538,944 B
  float* Cws         = (float*)(ws + 6635520);              // 3*3072*144*4 = 5,308,416 B
                                                            // total ws use: 11,943,936 B

  hipLaunchKernelGGL(k0_zero,  dim3(1296), dim3(256), 0, stream, Cws);
  hipLaunchKernelGGL(k1_prep,  dim3(48, 3), dim3(256), 0, stream, feat, W, av, Mt, Es);
  hipLaunchKernelGGL(k2a_pack, dim3(2048), dim3(256), 0, stream, adj, pk);
  hipLaunchKernelGGL(k2b_agg,  dim3(24, 3, 3), dim3(256), 0, stream, pk, Mt, Cws);
  hipLaunchKernelGGL(k3_final, dim3(3072), dim3(128), 0, stream, Cws, Es, bias, (float*)d_out);
}

// Round 11
// 67.796 us; speedup vs baseline: 1.3187x; 1.2671x over previous
//
#include <hip/hip_runtime.h>

typedef float  f32x4  __attribute__((ext_vector_type(4)));
typedef float  f32x2  __attribute__((ext_vector_type(2)));
typedef short  bf16x8 __attribute__((ext_vector_type(8)));
typedef int    i32x4  __attribute__((ext_vector_type(4)));

#define NNODE 3072
#define DIN   128
#define DOUT  128
#define NREL  3
#define NH    4
#define HD    32
#define KCH   48      // K chunks of 64
#define CHP   10240   // padded ushorts per B chunk (20480 B = 5 x 4KB stage units; 9216 real)

static __device__ __forceinline__ unsigned short f2bf(float v) {
  unsigned u = __builtin_bit_cast(unsigned, v);
  u += 0x7FFFu + ((u >> 16) & 1u);          // round-to-nearest-even
  return (unsigned short)(u >> 16);
}

// ---------------- K1: t = F * W_r^T, attention scalars, build B in MFMA-fragment order ----
// grid (48, 3), block 256. (numerics validated R2-R10)
__global__ __launch_bounds__(256, 1) void k1_prep(
    const float* __restrict__ feat, const float* __restrict__ W,
    const float* __restrict__ av, unsigned short* __restrict__ Mt,
    float* __restrict__ Es)
{
  const int jt = blockIdx.x;     // 0..47  (= K chunk index)
  const int r  = blockIdx.y;     // 0..2
  const int t  = threadIdx.x;    // 0..255
  const int jb = jt * 64;

  __shared__ float Wl[128 * 130];
  __shared__ float Fl[64 * 129];
  __shared__ float Tl[64 * 129];
  __shared__ float El[64 * 5];

  const float* Wr = W + r * DOUT * DIN;
  for (int idx = t * 4; idx < DOUT * DIN; idx += 1024) {
    float4 v = *(const float4*)(Wr + idx);
    int o = idx >> 7, k = idx & 127;
    float* d = Wl + o * 130 + k;
    d[0] = v.x; d[1] = v.y; d[2] = v.z; d[3] = v.w;
  }
  for (int idx = t * 4; idx < 64 * DIN; idx += 1024) {
    float4 v = *(const float4*)(feat + (size_t)jb * DIN + idx);
    int n = idx >> 7, k = idx & 127;
    float* d = Fl + n * 129 + k;
    d[0] = v.x; d[1] = v.y; d[2] = v.z; d[3] = v.w;
  }
  __syncthreads();

  {
    const int ng = t & 15, og = t >> 4;
    float acc[4][8] = {};
    for (int k = 0; k < DIN; k += 4) {
      float wv[4][8];
      #pragma unroll
      for (int oo = 0; oo < 8; ++oo) {
        const float* wr2 = Wl + (og * 8 + oo) * 130 + k;
        f32x2 a01 = *(const f32x2*)wr2;
        f32x2 a23 = *(const f32x2*)(wr2 + 2);
        wv[0][oo] = a01[0]; wv[1][oo] = a01[1];
        wv[2][oo] = a23[0]; wv[3][oo] = a23[1];
      }
      #pragma unroll
      for (int nn = 0; nn < 4; ++nn) {
        const float* fr = Fl + (ng * 4 + nn) * 129 + k;
        float f0 = fr[0], f1 = fr[1], f2 = fr[2], f3 = fr[3];
        #pragma unroll
        for (int oo = 0; oo < 8; ++oo) {
          float s = acc[nn][oo];
          s = fmaf(f0, wv[0][oo], s);
          s = fmaf(f1, wv[1][oo], s);
          s = fmaf(f2, wv[2][oo], s);
          s = fmaf(f3, wv[3][oo], s);
          acc[nn][oo] = s;
        }
      }
    }
    #pragma unroll
    for (int nn = 0; nn < 4; ++nn)
      #pragma unroll
      for (int oo = 0; oo < 8; ++oo)
        Tl[(ng * 4 + nn) * 129 + og * 8 + oo] = acc[nn][oo];
  }
  __syncthreads();

  {
    const int n = t & 63, h = t >> 6;
    const float* tr = Tl + n * 129 + h * HD;
    const float* as = av + r * 2 * HD;
    float ss = 0.f, sd = 0.f;
    #pragma unroll
    for (int d = 0; d < HD; ++d) {
      float tvv = tr[d];
      ss = fmaf(tvv, as[d],      ss);
      sd = fmaf(tvv, as[HD + d], sd);
    }
    Es[((size_t)r * NNODE + jb + n) * NH + h] = expf(ss);
    El[n * 5 + h] = expf(sd);
  }
  __syncthreads();

  {
    // B fragment order: chunk = [tile nt][step s][lane = k8*16 + (c&15)][elem = j&7]
    const int n = t & 63, cb = t >> 6;   // j = jb + n
    unsigned short* base = Mt + ((size_t)r * KCH + jt) * CHP;
    const int s = n >> 5, k8 = (n >> 3) & 3, elem = n & 7;
    const int lanebase = k8 * 16;
    #pragma unroll
    for (int ci = 0; ci < 36; ++ci) {
      int c = cb * 36 + ci;
      float v;
      if (c < DOUT)            v = Tl[n * 129 + c] * El[n * 5 + (c >> 5)];
      else if (c < DOUT + NH)  v = El[n * 5 + (c - DOUT)];
      else if (c == DOUT + NH) v = 1.0f;
      else                     v = 0.0f;
      int nt = c >> 4;
      base[(nt * 2 + s) * 512 + (lanebase + (c & 15)) * 8 + elem] = f2bf(v);
    }
  }
}

// ---------------- K2a: bit-pack adjacency, thread-coarse pure streamer ----------------
// grid 1728, block 256. Thread = one 64-int span: 16 independent dwordx4 (256 B/thread,
// 16 KB/wave contiguous), per-thread bit pack (adjacency is exactly {0,1}), one coalesced
// 8 B store (wave writes 512 B contiguous). No cross-lane ops, no drains.
__global__ __launch_bounds__(256) void k2a_pack(
    const int* __restrict__ adj, unsigned int* __restrict__ pk)
{
  const int idx = blockIdx.x * 256 + threadIdx.x;   // 0..442367 (9216 rows x 48 spans)
  const int row = idx / 48, span = idx - row * 48;
  const i32x4* src = (const i32x4*)(adj + (size_t)row * NNODE + span * 64);
  i32x4 v[16];
  #pragma unroll
  for (int q = 0; q < 16; ++q) v[q] = src[q];
  unsigned lo = 0, hi = 0;
  #pragma unroll
  for (int k = 0; k < 32; ++k) lo |= (unsigned)(v[k >> 2][k & 3] & 1) << k;
  #pragma unroll
  for (int k = 0; k < 32; ++k) hi |= (unsigned)(v[8 + (k >> 2)][k & 3] & 1) << k;
  *(unsigned long long*)(pk + (size_t)row * 96 + span * 2) =
      (unsigned long long)lo | ((unsigned long long)hi << 32);
}

// ---------------- K2b: bitpacked-A GEMM, M=128/K-split-3, LDS B pipeline, plain stores ----
// grid (24, 3, 3) = (mt, kq, r), block 256 = 4 waves. Block: 128 rows x 144 cols x 16 chunks.
// A bits: 18.4KB LDS, loaded once. B: 3 x 20KB LDS bufs, 5 x global_load_lds(16B)/thread/chunk,
// counted vmcnt(5) + raw s_barrier per chunk. Waves split M (32 rows each, all 9 col-tiles).
// Epilogue: plain stores into per-kq slot of Cp (full coverage -> no zero-init, no atomics).
#define EXPAND(d, dst) do {                                                \
    unsigned b_  = ((d) >> sh) & 0xFFu;                                    \
    unsigned lo_ = ((b_ & 0x0Fu) * 0x204081u) & 0x01010101u;               \
    unsigned hi_ = ((b_ >> 4)   * 0x204081u) & 0x01010101u;                \
    dst = __builtin_bit_cast(bf16x8, (i32x4){                              \
      (int)(__builtin_amdgcn_perm(0u, lo_, 0x0C010C00u) * 0x3F80u),        \
      (int)(__builtin_amdgcn_perm(0u, lo_, 0x0C030C02u) * 0x3F80u),        \
      (int)(__builtin_amdgcn_perm(0u, hi_, 0x0C010C00u) * 0x3F80u),        \
      (int)(__builtin_amdgcn_perm(0u, hi_, 0x0C030C02u) * 0x3F80u)});      \
  } while (0)

#define MF(a, b, c) __builtin_amdgcn_mfma_f32_16x16x32_bf16(a, b, c, 0, 0, 0)

__global__ __launch_bounds__(256, 2) void k2b_agg(
    const unsigned int* __restrict__ pk, const unsigned short* __restrict__ Mt,
    float* __restrict__ Cp)
{
  const int mt = blockIdx.x;    // 0..23  M-tile
  const int kq = blockIdx.y;    // 0..2   K-third (16 chunks)
  const int r  = blockIdx.z;    // 0..2
  const int t  = threadIdx.x;   // 0..255
  const int wv = t >> 6;
  const int l  = t & 63;
  const int l16 = l & 15, l4 = l >> 4;
  const int ib = mt * 128;
  const unsigned sh = (unsigned)l4 * 8u;

  __shared__ __align__(16) unsigned Al[128 * 36];           // 18432 B
  __shared__ __align__(16) unsigned short Bl[3][CHP];       // 61440 B

  // ---- prologue: A bits, rows ib..ib+127, uints [kq*32, +32) per row ----
  {
    const unsigned* pg = pk + ((size_t)r * NNODE + ib) * 96 + kq * 32;
    const int ri = t >> 1, half = (t & 1) * 16;
    const unsigned* src = pg + (size_t)ri * 96 + half;
    #pragma unroll
    for (int q = 0; q < 4; ++q)
      *(i32x4*)&Al[ri * 36 + half + q * 4] = *(const i32x4*)(src + q * 4);
  }

  const unsigned short* msrc = Mt + ((size_t)r * KCH + (size_t)kq * 16) * CHP;
  #define STAGE_B(kk, buf) do {                                                   \
    const unsigned short* s_ = msrc + (size_t)(kk) * CHP;                         \
    _Pragma("unroll")                                                             \
    for (int j_ = 0; j_ < 5; ++j_)                                                \
      __builtin_amdgcn_global_load_lds(                                           \
        (const __attribute__((address_space(1))) void*)(s_ + j_ * 2048 + t * 8),  \
        (__attribute__((address_space(3))) void*)&Bl[buf][j_ * 2048 + t * 8],     \
        16, 0, 0);                                                                \
  } while (0)

  f32x4 acc[2][9] = {};

  STAGE_B(0, 0);
  asm volatile("s_waitcnt vmcnt(0)");
  __syncthreads();           // A + chunk0 resident

  #pragma unroll 1
  for (int kk = 0; kk < 16; ++kk) {
    const int nk = (kk + 1 < 16) ? kk + 1 : 15;
    STAGE_B(nk, (kk + 1) % 3);
    __builtin_amdgcn_sched_barrier(0);
    asm volatile("s_waitcnt vmcnt(5)");      // chunk kk's 5 done; kk+1's 5 in flight
    __builtin_amdgcn_s_barrier();
    __builtin_amdgcn_sched_barrier(0);

    const unsigned short* Bc = &Bl[kk % 3][0];
    const unsigned d0 = Al[(wv * 32 + l16) * 36 + 2 * kk];
    const unsigned d1 = Al[(wv * 32 + l16) * 36 + 2 * kk + 1];
    const unsigned e0 = Al[(wv * 32 + 16 + l16) * 36 + 2 * kk];
    const unsigned e1 = Al[(wv * 32 + 16 + l16) * 36 + 2 * kk + 1];
    bf16x8 af0, af1;

    EXPAND(d0, af0); EXPAND(e0, af1);
    #pragma unroll
    for (int nt = 0; nt < 9; ++nt) {
      bf16x8 b = *(const bf16x8*)(Bc + (nt * 2 + 0) * 512 + l * 8);
      acc[0][nt] = MF(af0, b, acc[0][nt]);
      acc[1][nt] = MF(af1, b, acc[1][nt]);
    }
    EXPAND(d1, af0); EXPAND(e1, af1);
    #pragma unroll
    for (int nt = 0; nt < 9; ++nt) {
      bf16x8 b = *(const bf16x8*)(Bc + (nt * 2 + 1) * 512 + l * 8);
      acc[0][nt] = MF(af0, b, acc[0][nt]);
      acc[1][nt] = MF(af1, b, acc[1][nt]);
    }
  }
  asm volatile("s_waitcnt vmcnt(0)");   // retire dummy stage before exit

  // ---- epilogue: plain stores into per-kq slot (complete coverage) ----
  float* base = Cp + (((size_t)kq * NREL + r) * NNODE + ib + wv * 32) * 144;
  #pragma unroll
  for (int h = 0; h < 2; ++h)
    #pragma unroll
    for (int nt = 0; nt < 9; ++nt)
      #pragma unroll
      for (int j = 0; j < 4; ++j)
        base[(size_t)(h * 16 + l4 * 4 + j) * 144 + nt * 16 + l16] = acc[h][nt][j];
  #undef STAGE_B
}

// ---------------- K3: sum kq slots, finalize coef + mean + bias ----------------
// grid 3072, block 128: one output row per block.
__global__ __launch_bounds__(128, 1) void k3_final(
    const float* __restrict__ Cp, const float* __restrict__ Es,
    const float* __restrict__ bias, float* __restrict__ out)
{
  const int i = blockIdx.x;
  const int t = threadIdx.x;
  __shared__ float coef[12];
  if (t < 12) {
    int r = t >> 2, h = t & 3;
    float V = 0.f, dg = 0.f;
    #pragma unroll
    for (int kq = 0; kq < 3; ++kq) {
      const float* Ci = Cp + (((size_t)kq * NREL + r) * NNODE + i) * 144;
      V  += Ci[DOUT + h];
      dg += Ci[DOUT + NH];
    }
    float es = Es[((size_t)r * NNODE + i) * NH + h];
    coef[t] = es / fmaf(es, V, (float)NNODE - dg) * (1.0f / NREL);
  }
  __syncthreads();
  const int h = t >> 5;
  float s = 0.f;
  #pragma unroll
  for (int r = 0; r < 3; ++r) {
    float cr = coef[r * 4 + h], sr = 0.f;
    #pragma unroll
    for (int kq = 0; kq < 3; ++kq)
      sr += Cp[(((size_t)kq * NREL + r) * NNODE + i) * 144 + t];
    s += cr * sr;
  }
  out[(size_t)i * DOUT + t] = s + bias[t];
}

extern "C" void kernel_launch(void* const* d_in, const int* in_sizes, int n_in,
                              void* d_out, int out_size, void* d_ws, size_t ws_size,
                              hipStream_t stream) {
  const float* feat = (const float*)d_in[0];
  const int*   adj  = (const int*)d_in[1];
  const float* W    = (const float*)d_in[2];
  const float* av   = (const float*)d_in[3];
  const float* bias = (const float*)d_in[4];

  char* ws = (char*)d_ws;
  unsigned short* Mt = (unsigned short*)ws;                 // 3*48*10240*2 = 2,949,120 B
  float* Es          = (float*)(ws + 2949120);              // 3*3072*4*4   =   147,456 B
  unsigned int* pk   = (unsigned int*)(ws + 3096576);       // 9216*96*4    = 3,538,944 B
  float* Cp          = (float*)(ws + 6635520);              // 3*3*3072*144*4 = 15,925,248 B
                                                            // total ws use: 22,560,768 B

  hipLaunchKernelGGL(k1_prep,  dim3(48, 3), dim3(256), 0, stream, feat, W, av, Mt, Es);
  hipLaunchKernelGGL(k2a_pack, dim3(1728), dim3(256), 0, stream, adj, pk);
  hipLaunchKernelGGL(k2b_agg,  dim3(24, 3, 3), dim3(256), 0, stream, pk, Mt, Cp);
  hipLaunchKernelGGL(k3_final, dim3(3072), dim3(128), 0, stream, Cp, Es, bias, (float*)d_out);
}